// Round 17
// baseline (212.456 us; speedup 1.0000x reference)
//
#include <hip/hip_runtime.h>
#include <math.h>

#define BB     1024
#define CC     256
#define HWN    361
#define SEH    64
#define P3C    768
#define SLICE  (CC * HWN)      // 92416 floats per batch row
#define NW     16

typedef _Float16 f16x2 __attribute__((ext_vector_type(2)));

__device__ __forceinline__ unsigned pack2(float a, float b) {
    f16x2 h; h[0] = (_Float16)a; h[1] = (_Float16)b;
    return __builtin_bit_cast(unsigned, h);
}

// Pool rows k,k+1 (wave-local) of batch-row base XB into pinned payload PK,
// using mask buffer MB; accumulate-as-loaded to keep live f32 count ~4.
#define POOL2(PK, MB, XB, INVD, BS, k)                                        \
{                                                                             \
    const int c0_ = wv * 16 + (k);                                            \
    const float* r0_ = (XB) + c0_ * HWN;                                      \
    const float* r1_ = r0_ + HWN;                                             \
    float s0_ = 0.0f, s1_ = 0.0f, x0_ = NINF, x1_ = NINF;                     \
    float vp_, wp_, v_, w_;                                                   \
    vp_ = r0_[lane];        wp_ = r1_[lane];                                  \
    { const float pen_ = (1.0f - (MB)[lane]) * -5000.0f;                      \
      s0_ += vp_; x0_ = fmaxf(x0_, vp_ + pen_);                               \
      s1_ += wp_; x1_ = fmaxf(x1_, wp_ + pen_); }                             \
    v_ = r0_[lane + 64];    w_ = r1_[lane + 64];                              \
    { const float pen_ = (1.0f - (MB)[lane + 64]) * -5000.0f;                 \
      s0_ += v_; x0_ = fmaxf(x0_, v_ + pen_);                                 \
      s1_ += w_; x1_ = fmaxf(x1_, w_ + pen_); }                               \
    PK[(k)][0]     = pack2(vp_, v_);                                          \
    PK[(k) + 1][0] = pack2(wp_, w_);                                          \
    vp_ = r0_[lane + 128];  wp_ = r1_[lane + 128];                            \
    { const float pen_ = (1.0f - (MB)[lane + 128]) * -5000.0f;                \
      s0_ += vp_; x0_ = fmaxf(x0_, vp_ + pen_);                               \
      s1_ += wp_; x1_ = fmaxf(x1_, wp_ + pen_); }                             \
    v_ = r0_[lane + 192];   w_ = r1_[lane + 192];                             \
    { const float pen_ = (1.0f - (MB)[lane + 192]) * -5000.0f;                \
      s0_ += v_; x0_ = fmaxf(x0_, v_ + pen_);                                 \
      s1_ += w_; x1_ = fmaxf(x1_, w_ + pen_); }                               \
    PK[(k)][1]     = pack2(vp_, v_);                                          \
    PK[(k) + 1][1] = pack2(wp_, w_);                                          \
    vp_ = r0_[lane + 256];  wp_ = r1_[lane + 256];                            \
    { const float pen_ = (1.0f - (MB)[lane + 256]) * -5000.0f;                \
      s0_ += vp_; x0_ = fmaxf(x0_, vp_ + pen_);                               \
      s1_ += wp_; x1_ = fmaxf(x1_, wp_ + pen_); }                             \
    v_ = r0_[a5];           w_ = r1_[a5];                                     \
    if (tail) {                                                               \
      const float pen_ = (1.0f - (MB)[i5]) * -5000.0f;                        \
      s0_ += v_; x0_ = fmaxf(x0_, v_ + pen_);                                 \
      s1_ += w_; x1_ = fmaxf(x1_, w_ + pen_);                                 \
    }                                                                         \
    PK[(k)][2]     = pack2(vp_, v_);                                          \
    PK[(k) + 1][2] = pack2(wp_, w_);                                          \
    asm volatile("" : "+v"(PK[(k)][0]), "+v"(PK[(k)][1]), "+v"(PK[(k)][2]),   \
                      "+v"(PK[(k)+1][0]), "+v"(PK[(k)+1][1]),                 \
                      "+v"(PK[(k)+1][2]));                                    \
    _Pragma("unroll")                                                         \
    for (int off_ = 32; off_; off_ >>= 1) {                                   \
        s0_ += __shfl_xor(s0_, off_);  x0_ = fmaxf(x0_, __shfl_xor(x0_, off_));\
        s1_ += __shfl_xor(s1_, off_);  x1_ = fmaxf(x1_, __shfl_xor(x1_, off_));\
    }                                                                         \
    if (lane == 0) {                                                          \
        const float mean0_ = s0_ * (INVD), mean1_ = s1_ * (INVD);             \
        p_s[c0_]           = mean0_;                                          \
        p_s[256 + c0_]     = mean0_ * (BS);                                   \
        p_s[512 + c0_]     = x0_;                                             \
        p_s[c0_ + 1]       = mean1_;                                          \
        p_s[256 + c0_ + 1] = mean1_ * (BS);                                   \
        p_s[512 + c0_ + 1] = x1_;                                             \
    }                                                                         \
}

// Apply rows k,k+1 of OB from pinned payload PK (zero reads of x).
#define APPLY2(PK, MB, GS, BES, OB, k)                                        \
{                                                                             \
    _Pragma("unroll")                                                         \
    for (int r_ = 0; r_ < 2; ++r_) {                                          \
        const int c_ = wv * 16 + (k) + r_;                                    \
        const float g_  = (GS)[c_];                                           \
        const float be_ = (BES)[c_];                                          \
        float* orow_ = (OB) + c_ * HWN;                                       \
        const f16x2 h0_ = __builtin_bit_cast(f16x2, PK[(k) + r_][0]);         \
        const f16x2 h1_ = __builtin_bit_cast(f16x2, PK[(k) + r_][1]);         \
        const f16x2 h2_ = __builtin_bit_cast(f16x2, PK[(k) + r_][2]);         \
        orow_[lane]       = fmaf(g_, (float)h0_[0], be_) * (MB)[lane];        \
        orow_[lane + 64]  = fmaf(g_, (float)h0_[1], be_) * (MB)[lane + 64];   \
        orow_[lane + 128] = fmaf(g_, (float)h1_[0], be_) * (MB)[lane + 128];  \
        orow_[lane + 192] = fmaf(g_, (float)h1_[1], be_) * (MB)[lane + 192];  \
        orow_[lane + 256] = fmaf(g_, (float)h2_[0], be_) * (MB)[lane + 256];  \
        if (tail)                                                             \
            orow_[i5]     = fmaf(g_, (float)h2_[1], be_) * (MB)[i5];          \
    }                                                                         \
}

__device__ __forceinline__ void mlp_ph(const int tid,
        const float* __restrict__ w1, const float* __restrict__ b1,
        const float* __restrict__ w2, const float* __restrict__ b2,
        const float* p_s, float* part_s, float* hid_s,
        float* g_out, float* be_out) {
    {
        const int q = tid >> 6, s = tid & 63;
        const float* w1r = w1  + s * P3C + q * 48;
        const float* pp  = p_s + q * 48;
        float acc = 0.0f;
        #pragma unroll 8
        for (int j = 0; j < 48; ++j) acc = fmaf(pp[j], w1r[j], acc);
        part_s[q * SEH + s] = acc;
    }
    __syncthreads();
    if (tid < SEH) {
        float h = b1[tid];
        #pragma unroll
        for (int q = 0; q < NW; ++q) h += part_s[q * SEH + tid];
        hid_s[tid] = fmaxf(h, 0.0f);
    }
    __syncthreads();
    if (tid < 512) {
        float a = b2[tid];
        const float* w2r = w2 + (size_t)tid * SEH;
        #pragma unroll 8
        for (int ss = 0; ss < SEH; ++ss) a = fmaf(hid_s[ss], w2r[ss], a);
        if (tid < 256) g_out[tid]        = 1.0f / (1.0f + __expf(-a));
        else           be_out[tid - 256] = a;
    }
    __syncthreads();
}

// One block (16 waves) per 4 batch rows; grid = 256 (1 block/CU).
// Software pipeline: pool(b0);MLP; [apply(b_i) INTERLEAVED with pool(b_{i+1})]
// x3; MLP each; apply(b3). The middle phases issue loads AND stores in the
// same loop -> mixed HBM traffic (copy-shaped) instead of read/write epochs.
// Payload double-buffered as pinned f16 pairs (2 x 48 VGPR).
__global__ __launch_bounds__(1024, 4) void k_se_pipe(
        const float* __restrict__ x,
        const float* __restrict__ mask,
        const float* __restrict__ msum,
        const float* __restrict__ msqrt,
        const float* __restrict__ w1,
        const float* __restrict__ b1,
        const float* __restrict__ w2,
        const float* __restrict__ b2,
        float* __restrict__ out) {
    __shared__ float m_s[2][HWN];
    __shared__ float p_s[P3C];
    __shared__ float part_s[NW * SEH];
    __shared__ float hid_s[SEH];
    __shared__ float g_s[2][CC];
    __shared__ float be_s[2][CC];

    const int tid  = threadIdx.x;
    const int lane = tid & 63;
    const int wv   = tid >> 6;
    const int b0   = blockIdx.x * 4;

    const float NINF = -__builtin_inff();
    const int  i5   = lane + 320;
    const int  a5   = (i5 < HWN) ? i5 : (HWN - 1);
    const bool tail = (lane < 41);                 // 361 = 5*64 + 41

    unsigned pkA[16][3], pkB[16][3];

    // ---------- prologue: pool(b0) -> pkA, MLP(b0) -> buf0 ----------
    if (tid < HWN) m_s[0][tid] = mask[(size_t)b0 * HWN + tid];
    __syncthreads();
    {
        const float invd = 1.0f / msum[b0];
        const float bs   = (msqrt[b0] - 14.0f) * 0.1f;
        const float* xb  = x + (size_t)b0 * SLICE;
        #pragma unroll
        for (int k = 0; k < 16; k += 2) POOL2(pkA, m_s[0], xb, invd, bs, k)
    }
    __syncthreads();
    mlp_ph(tid, w1, b1, w2, b2, p_s, part_s, hid_s, g_s[0], be_s[0]);

    // ---------- iter 0: apply(b0) <- pkA/buf0  ||  pool(b1) -> pkB/buf1 ----
    if (tid < HWN) m_s[1][tid] = mask[(size_t)(b0 + 1) * HWN + tid];
    __syncthreads();
    {
        const float invd = 1.0f / msum[b0 + 1];
        const float bs   = (msqrt[b0 + 1] - 14.0f) * 0.1f;
        const float* xbn = x   + (size_t)(b0 + 1) * SLICE;
        float*       obc = out + (size_t)(b0 + 0) * SLICE;
        #pragma unroll
        for (int k = 0; k < 16; k += 2) {
            POOL2(pkB, m_s[1], xbn, invd, bs, k)
            APPLY2(pkA, m_s[0], g_s[0], be_s[0], obc, k)
        }
    }
    __syncthreads();
    mlp_ph(tid, w1, b1, w2, b2, p_s, part_s, hid_s, g_s[1], be_s[1]);

    // ---------- iter 1: apply(b1) <- pkB/buf1  ||  pool(b2) -> pkA/buf0 ----
    if (tid < HWN) m_s[0][tid] = mask[(size_t)(b0 + 2) * HWN + tid];
    __syncthreads();
    {
        const float invd = 1.0f / msum[b0 + 2];
        const float bs   = (msqrt[b0 + 2] - 14.0f) * 0.1f;
        const float* xbn = x   + (size_t)(b0 + 2) * SLICE;
        float*       obc = out + (size_t)(b0 + 1) * SLICE;
        #pragma unroll
        for (int k = 0; k < 16; k += 2) {
            POOL2(pkA, m_s[0], xbn, invd, bs, k)
            APPLY2(pkB, m_s[1], g_s[1], be_s[1], obc, k)
        }
    }
    __syncthreads();
    mlp_ph(tid, w1, b1, w2, b2, p_s, part_s, hid_s, g_s[0], be_s[0]);

    // ---------- iter 2: apply(b2) <- pkA/buf0  ||  pool(b3) -> pkB/buf1 ----
    if (tid < HWN) m_s[1][tid] = mask[(size_t)(b0 + 3) * HWN + tid];
    __syncthreads();
    {
        const float invd = 1.0f / msum[b0 + 3];
        const float bs   = (msqrt[b0 + 3] - 14.0f) * 0.1f;
        const float* xbn = x   + (size_t)(b0 + 3) * SLICE;
        float*       obc = out + (size_t)(b0 + 2) * SLICE;
        #pragma unroll
        for (int k = 0; k < 16; k += 2) {
            POOL2(pkB, m_s[1], xbn, invd, bs, k)
            APPLY2(pkA, m_s[0], g_s[0], be_s[0], obc, k)
        }
    }
    __syncthreads();
    mlp_ph(tid, w1, b1, w2, b2, p_s, part_s, hid_s, g_s[1], be_s[1]);

    // ---------- epilogue: apply(b3) <- pkB/buf1 ----------
    {
        float* obc = out + (size_t)(b0 + 3) * SLICE;
        #pragma unroll
        for (int k = 0; k < 16; k += 2)
            APPLY2(pkB, m_s[1], g_s[1], be_s[1], obc, k)
    }
}

extern "C" void kernel_launch(void* const* d_in, const int* in_sizes, int n_in,
                              void* d_out, int out_size, void* d_ws, size_t ws_size,
                              hipStream_t stream) {
    const float* x     = (const float*)d_in[0];
    const float* mask  = (const float*)d_in[1];
    const float* msum  = (const float*)d_in[2];
    const float* msqrt = (const float*)d_in[3];
    const float* w1    = (const float*)d_in[4];
    const float* b1    = (const float*)d_in[5];
    const float* w2    = (const float*)d_in[6];
    const float* b2    = (const float*)d_in[7];
    float* out = (float*)d_out;

    k_se_pipe<<<BB / 4, 1024, 0, stream>>>(x, mask, msum, msqrt,
                                           w1, b1, w2, b2, out);
}